// Round 5
// baseline (1008.295 us; speedup 1.0000x reference)
//
#include <hip/hip_runtime.h>

#define N_ROWS 131072
#define KCODES 1024
#define DIM 64
#define BLOCK 256
#define ROWS_PB 128
#define KHALF (KCODES / 2)

// ||c||^2 for all codes, computed once by a tiny pre-kernel with the exact
// pairwise bit-formula the passing kernel used.
__device__ float g_c2[KCODES];

__global__ void __launch_bounds__(BLOCK)
c2_pre(const float* __restrict__ cb)
{
#pragma clang fp contract(off)
    const int code = blockIdx.x * BLOCK + threadIdx.x;
    const float* c = cb + code * DIM;
    float r0 = c[0]*c[0], r1 = c[1]*c[1], r2 = c[2]*c[2], r3 = c[3]*c[3];
    float r4 = c[4]*c[4], r5 = c[5]*c[5], r6 = c[6]*c[6], r7 = c[7]*c[7];
#pragma unroll
    for (int i = 1; i < 8; ++i) {
        r0 = r0 + c[i*8+0]*c[i*8+0];
        r1 = r1 + c[i*8+1]*c[i*8+1];
        r2 = r2 + c[i*8+2]*c[i*8+2];
        r3 = r3 + c[i*8+3]*c[i*8+3];
        r4 = r4 + c[i*8+4]*c[i*8+4];
        r5 = r5 + c[i*8+5]*c[i*8+5];
        r6 = r6 + c[i*8+6]*c[i*8+6];
        r7 = r7 + c[i*8+7]*c[i*8+7];
    }
    g_c2[code] = ((r0 + r1) + (r2 + r3)) + ((r4 + r5) + (r6 + r7));
}

// h: [32, 64, 64, 64] fp32 (B, D, H, W); codebook: [1024, 64] fp32
// out: z[131072] as float ++ q[131072*64] fp32
//
// Row-per-lane: each lane owns one x-row in 64 VGPRs. Waves 0,1 = rows
// 0..127 with k in [0,512); waves 2,3 = same rows, k in [512,1024).
// Codebook comes in as uniform-address vector loads (L1/L2 broadcast),
// ILP-2 across codes k,k+1 (independent fma chains; compared in k order
// => np first-index ties preserved).
//
// ROUND-5 FIX (the real one): rounds 2-4 the compiler SANK the x-row
// loads into the k-loop (WRITE_SIZE showed zero scratch => no spill; it
// rematerialized from global instead, VGPR_Count=48, every fma waiting
// on cache latency). Two countermeasures:
//   (a) amdgpu_waves_per_eu(2,2): 256-VGPR budget + occupancy target 2
//       (the baseline's proven non-sinking setting, VGPR=116 there).
//   (b) a memory-clobber asm fence between the x loads and the k-loop:
//       loads cannot legally move past it, so sinking is off the table.
__global__ void
__attribute__((amdgpu_flat_work_group_size(256, 256), amdgpu_waves_per_eu(2, 2)))
vq_main(const float* __restrict__ h,
        const float* __restrict__ cb,
        float* __restrict__ z_out,
        float* __restrict__ q_out)
{
    __shared__ float mbd[ROWS_PB];    // khalf0 best dist
    __shared__ int   mbk[ROWS_PB];    // khalf0 best idx
    __shared__ int   s_idx[ROWS_PB];  // final idx for q gather

    const int tid   = threadIdx.x;
    const int lane  = tid & 63;
    const int wave  = tid >> 6;            // 0..3
    const int khalf = wave >> 1;           // 0: k in [0,512), 1: [512,1024)
    const int rloc  = (wave & 1) * 64 + lane;   // 0..127
    const int row0  = blockIdx.x * ROWS_PB;
    const int row   = row0 + rloc;
    const int bb    = row >> 12;
    const int yx    = row & 4095;

    // ---- x row into registers (coalesced across lanes for each d) ----
    float xr[DIM];
    {
        const float* hb = h + (size_t)bb * (DIM * 4096) + yx;
#pragma unroll
        for (int d = 0; d < DIM; ++d)
            xr[d] = hb[(size_t)d * 4096];
    }
    // Pin the x loads HERE: loads cannot sink past a memory clobber.
    asm volatile("" ::: "memory");

    // ---- Sv = ||x||^2, exact pairwise bit-formula as before ----
    float Sv;
    {
#pragma clang fp contract(off)
        float r0 = xr[0]*xr[0], r1 = xr[1]*xr[1], r2 = xr[2]*xr[2], r3 = xr[3]*xr[3];
        float r4 = xr[4]*xr[4], r5 = xr[5]*xr[5], r6 = xr[6]*xr[6], r7 = xr[7]*xr[7];
#pragma unroll
        for (int i = 1; i < 8; ++i) {
            r0 = r0 + xr[i*8+0]*xr[i*8+0];
            r1 = r1 + xr[i*8+1]*xr[i*8+1];
            r2 = r2 + xr[i*8+2]*xr[i*8+2];
            r3 = r3 + xr[i*8+3]*xr[i*8+3];
            r4 = r4 + xr[i*8+4]*xr[i*8+4];
            r5 = r5 + xr[i*8+5]*xr[i*8+5];
            r6 = r6 + xr[i*8+6]*xr[i*8+6];
            r7 = r7 + xr[i*8+7]*xr[i*8+7];
        }
        Sv = ((r0 + r1) + (r2 + r3)) + ((r4 + r5) + (r6 + r7));
    }

    // ---- argmin over this wave's k-half, two codes in flight ----
    float bd = 3.4e38f;
    int   bk = 0;
    const int kbeg = khalf * KHALF;
    const float4* cb4 = (const float4*)cb;

#pragma unroll 1
    for (int kp = 0; kp < KHALF; kp += 2) {
        const int k = kbeg + kp;
        const float4* cA = cb4 + (size_t)k * 16;   // code k;   code k+1 at +16
        const float c2A = g_c2[k];                 // hoisted: latency under fmas
        const float c2B = g_c2[k + 1];

        float accA = 0.0f, accB = 0.0f;
#pragma unroll
        for (int j = 0; j < 16; ++j) {
            const float4 a = cA[j];
            const float4 b = cA[16 + j];
            accA = __builtin_fmaf(xr[4*j+0], a.x, accA);
            accA = __builtin_fmaf(xr[4*j+1], a.y, accA);
            accA = __builtin_fmaf(xr[4*j+2], a.z, accA);
            accA = __builtin_fmaf(xr[4*j+3], a.w, accA);
            accB = __builtin_fmaf(xr[4*j+0], b.x, accB);
            accB = __builtin_fmaf(xr[4*j+1], b.y, accB);
            accB = __builtin_fmaf(xr[4*j+2], b.z, accB);
            accB = __builtin_fmaf(xr[4*j+3], b.w, accB);
        }

        {
#pragma clang fp contract(off)
            const float tA  = 2.0f * accA;   // exact
            const float uA  = Sv - tA;       // rounded like np
            const float d2A = uA + c2A;
            if (d2A < bd) { bd = d2A; bk = k; }
            const float tB  = 2.0f * accB;
            const float uB  = Sv - tB;
            const float d2B = uB + c2B;
            if (d2B < bd) { bd = d2B; bk = k + 1; }
        }
    }

    // ---- merge k-halves: khalf0 wins ties (smaller k) => np first-index ----
    if (khalf == 0) { mbd[rloc] = bd; mbk[rloc] = bk; }
    __syncthreads();
    if (khalf == 1) {
        const float d0  = mbd[rloc];
        const int   kk0 = mbk[rloc];
        const int   fk  = (bd < d0) ? bk : kk0;
        z_out[row]  = (float)fk;
        s_idx[rloc] = fk;
    }
    __syncthreads();

    // ---- q gather: bit-exact codebook rows, coalesced float4 stores ----
    float4* q4 = (float4*)q_out;
#pragma unroll
    for (int it = 0; it < 8; ++it) {
        const int slot = it * BLOCK + tid;    // 0..2047
        const int rl   = slot >> 4;           // row 0..127
        const int c4   = slot & 15;
        q4[(size_t)(row0 + rl) * 16 + c4] = cb4[(size_t)s_idx[rl] * 16 + c4];
    }
}

extern "C" void kernel_launch(void* const* d_in, const int* in_sizes, int n_in,
                              void* d_out, int out_size, void* d_ws, size_t ws_size,
                              hipStream_t stream) {
    const float* h  = (const float*)d_in[0];
    const float* cb = (const float*)d_in[1];
    float* out   = (float*)d_out;
    float* z_out = out;              // 131072 floats
    float* q_out = out + N_ROWS;     // 131072*64 floats
    (void)d_ws; (void)ws_size;

    c2_pre<<<dim3(KCODES / BLOCK), dim3(BLOCK), 0, stream>>>(cb);
    vq_main<<<dim3(N_ROWS / ROWS_PB), dim3(BLOCK), 0, stream>>>(h, cb, z_out, q_out);
}

// Round 6
// 370.727 us; speedup vs baseline: 2.7198x; 2.7198x over previous
//
#include <hip/hip_runtime.h>

#define N_ROWS 131072
#define KCODES 1024
#define DIM 64
#define BLOCK 256
#define ROWS_PB 128
#define KHALF (KCODES / 2)

// ||c||^2 for all codes, computed once by a tiny pre-kernel with the exact
// pairwise bit-formula the passing kernel used.
__device__ float g_c2[KCODES];

__global__ void __launch_bounds__(BLOCK)
c2_pre(const float* __restrict__ cb)
{
#pragma clang fp contract(off)
    const int code = blockIdx.x * BLOCK + threadIdx.x;
    const float* c = cb + code * DIM;
    float r0 = c[0]*c[0], r1 = c[1]*c[1], r2 = c[2]*c[2], r3 = c[3]*c[3];
    float r4 = c[4]*c[4], r5 = c[5]*c[5], r6 = c[6]*c[6], r7 = c[7]*c[7];
#pragma unroll
    for (int i = 1; i < 8; ++i) {
        r0 = r0 + c[i*8+0]*c[i*8+0];
        r1 = r1 + c[i*8+1]*c[i*8+1];
        r2 = r2 + c[i*8+2]*c[i*8+2];
        r3 = r3 + c[i*8+3]*c[i*8+3];
        r4 = r4 + c[i*8+4]*c[i*8+4];
        r5 = r5 + c[i*8+5]*c[i*8+5];
        r6 = r6 + c[i*8+6]*c[i*8+6];
        r7 = r7 + c[i*8+7]*c[i*8+7];
    }
    g_c2[code] = ((r0 + r1) + (r2 + r3)) + ((r4 + r5) + (r6 + r7));
}

typedef float f32x16 __attribute__((ext_vector_type(16)));
typedef float f32x2  __attribute__((ext_vector_type(2)));

// ROUND-6: rounds 2-5 proved time is invariant to xr residency (48 vs 104
// VGPR, same 995us) => bottleneck is codebook delivery: the compiler never
// scalarized the uniform loads (tid-derived khalf taints divergence
// analysis), so every code row moved as per-lane global_load_dwordx4 with
// 64-way return replication (~256 B/FMA vs the LDS kernel's 1 B/FMA).
// Fix: hand-rolled s_load_dwordx16 via inline asm, address built from
// readfirstlane => genuine SMEM broadcast (512B/pair per WAVE), FMAs read
// the code value from an SGPR operand directly. SGPR file can't hold two
// full rows (128), so each code-pair runs as two 32-dim chunks (64 SGPRs
// live) with one lgkmcnt(0) each (SMEM returns are out-of-order; counted
// lgkm waits are unsafe). 1024 blocks = 4/CU = 4 waves/SIMD hides the
// per-chunk SMEM stall.
__global__ void
__attribute__((amdgpu_flat_work_group_size(256, 256), amdgpu_waves_per_eu(4, 4)))
vq_main(const float* __restrict__ h,
        const float* __restrict__ cb,
        float* __restrict__ z_out,
        float* __restrict__ q_out)
{
    __shared__ float mbd[ROWS_PB];    // khalf0 best dist
    __shared__ int   mbk[ROWS_PB];    // khalf0 best idx
    __shared__ int   s_idx[ROWS_PB];  // final idx for q gather

    const int tid   = threadIdx.x;
    const int lane  = tid & 63;
    const int wave  = tid >> 6;            // 0..3
    const int khalf = wave >> 1;           // 0: k in [0,512), 1: [512,1024)
    const int rloc  = (wave & 1) * 64 + lane;   // 0..127
    const int row0  = blockIdx.x * ROWS_PB;
    const int row   = row0 + rloc;
    const int bb    = row >> 12;
    const int yx    = row & 4095;

    // ---- x row into registers (coalesced across lanes for each d) ----
    float xr[DIM];
    {
        const float* hb = h + (size_t)bb * (DIM * 4096) + yx;
#pragma unroll
        for (int d = 0; d < DIM; ++d)
            xr[d] = hb[(size_t)d * 4096];
    }
    // Pin the x loads here (r5 lesson: without this they sink into the loop).
    asm volatile("" ::: "memory");

    // ---- Sv = ||x||^2, exact pairwise bit-formula as before ----
    float Sv;
    {
#pragma clang fp contract(off)
        float r0 = xr[0]*xr[0], r1 = xr[1]*xr[1], r2 = xr[2]*xr[2], r3 = xr[3]*xr[3];
        float r4 = xr[4]*xr[4], r5 = xr[5]*xr[5], r6 = xr[6]*xr[6], r7 = xr[7]*xr[7];
#pragma unroll
        for (int i = 1; i < 8; ++i) {
            r0 = r0 + xr[i*8+0]*xr[i*8+0];
            r1 = r1 + xr[i*8+1]*xr[i*8+1];
            r2 = r2 + xr[i*8+2]*xr[i*8+2];
            r3 = r3 + xr[i*8+3]*xr[i*8+3];
            r4 = r4 + xr[i*8+4]*xr[i*8+4];
            r5 = r5 + xr[i*8+5]*xr[i*8+5];
            r6 = r6 + xr[i*8+6]*xr[i*8+6];
            r7 = r7 + xr[i*8+7]*xr[i*8+7];
        }
        Sv = ((r0 + r1) + (r2 + r3)) + ((r4 + r5) + (r6 + r7));
    }

    // Wave-uniform k-base, provably scalar via readfirstlane.
    const int kb = __builtin_amdgcn_readfirstlane(khalf) * KHALF;
    const float* c2base = (const float*)g_c2;

    float bd = 3.4e38f;
    int   bk = 0;

#pragma unroll 1
    for (int kp = 0; kp < KHALF; kp += 2) {
        const int k = kb + kp;
        const float* cp  = cb + (size_t)k * DIM;      // uniform: kernarg + scalar
        const float* c2p = c2base + k;

        // ---- chunk 0: dims 0..31 of codes k (offs 0,64) and k+1 (256,320) ----
        f32x16 a0, b0, a1, b1; f32x2 cc;
        asm volatile(
            "s_load_dwordx16 %0, %5, 0\n\t"
            "s_load_dwordx16 %1, %5, 256\n\t"
            "s_load_dwordx16 %2, %5, 64\n\t"
            "s_load_dwordx16 %3, %5, 320\n\t"
            "s_load_dwordx2  %4, %6, 0\n\t"
            "s_waitcnt lgkmcnt(0)"
            : "=&s"(a0), "=&s"(b0), "=&s"(a1), "=&s"(b1), "=&s"(cc)
            : "s"(cp), "s"(c2p));

        float accA = 0.0f, accB = 0.0f;
#pragma unroll
        for (int j = 0; j < 16; ++j) {
            accA = __builtin_fmaf(xr[j], a0[j], accA);
            accB = __builtin_fmaf(xr[j], b0[j], accB);
        }
#pragma unroll
        for (int j = 0; j < 16; ++j) {
            accA = __builtin_fmaf(xr[16 + j], a1[j], accA);
            accB = __builtin_fmaf(xr[16 + j], b1[j], accB);
        }

        // ---- chunk 1: dims 32..63 of codes k (128,192) and k+1 (384,448) ----
        f32x16 a2, b2, a3, b3;
        asm volatile(
            "s_load_dwordx16 %0, %4, 128\n\t"
            "s_load_dwordx16 %1, %4, 384\n\t"
            "s_load_dwordx16 %2, %4, 192\n\t"
            "s_load_dwordx16 %3, %4, 448\n\t"
            "s_waitcnt lgkmcnt(0)"
            : "=&s"(a2), "=&s"(b2), "=&s"(a3), "=&s"(b3)
            : "s"(cp));
#pragma unroll
        for (int j = 0; j < 16; ++j) {
            accA = __builtin_fmaf(xr[32 + j], a2[j], accA);
            accB = __builtin_fmaf(xr[32 + j], b2[j], accB);
        }
#pragma unroll
        for (int j = 0; j < 16; ++j) {
            accA = __builtin_fmaf(xr[48 + j], a3[j], accA);
            accB = __builtin_fmaf(xr[48 + j], b3[j], accB);
        }

        // ---- exact epilogue; A (k) before B (k+1) keeps first-index ties ----
        {
#pragma clang fp contract(off)
            const float tA  = 2.0f * accA;   // exact
            const float uA  = Sv - tA;       // rounded like np
            const float d2A = uA + cc[0];
            if (d2A < bd) { bd = d2A; bk = k; }
            const float tB  = 2.0f * accB;
            const float uB  = Sv - tB;
            const float d2B = uB + cc[1];
            if (d2B < bd) { bd = d2B; bk = k + 1; }
        }
    }

    // ---- merge k-halves: khalf0 wins ties (smaller k) => np first-index ----
    if (khalf == 0) { mbd[rloc] = bd; mbk[rloc] = bk; }
    __syncthreads();
    if (khalf == 1) {
        const float d0  = mbd[rloc];
        const int   kk0 = mbk[rloc];
        const int   fk  = (bd < d0) ? bk : kk0;
        z_out[row]  = (float)fk;
        s_idx[rloc] = fk;
    }
    __syncthreads();

    // ---- q gather: bit-exact codebook rows, coalesced float4 stores ----
    const float4* cb4 = (const float4*)cb;
    float4* q4 = (float4*)q_out;
#pragma unroll
    for (int it = 0; it < 8; ++it) {
        const int slot = it * BLOCK + tid;    // 0..2047
        const int rl   = slot >> 4;           // row 0..127
        const int c4   = slot & 15;
        q4[(size_t)(row0 + rl) * 16 + c4] = cb4[(size_t)s_idx[rl] * 16 + c4];
    }
}

extern "C" void kernel_launch(void* const* d_in, const int* in_sizes, int n_in,
                              void* d_out, int out_size, void* d_ws, size_t ws_size,
                              hipStream_t stream) {
    const float* h  = (const float*)d_in[0];
    const float* cb = (const float*)d_in[1];
    float* out   = (float*)d_out;
    float* z_out = out;              // 131072 floats
    float* q_out = out + N_ROWS;     // 131072*64 floats
    (void)d_ws; (void)ws_size;

    c2_pre<<<dim3(KCODES / BLOCK), dim3(BLOCK), 0, stream>>>(cb);
    vq_main<<<dim3(N_ROWS / ROWS_PB), dim3(BLOCK), 0, stream>>>(h, cb, z_out, q_out);
}